// Round 15
// baseline (55.099 us; speedup 1.0000x reference)
//
#include <hip/hip_runtime.h>
#include <hip/hip_bf16.h>
#include <stdint.h>

// Problem constants: B=2, L=2048, E=1024, H=16, HD=64, G=4.
#define L_SEQ 2048
#define MTOT  4096   // B*L
#define EDIM  1024

typedef __attribute__((ext_vector_type(8))) short bf16x8;    // 8 bf16 (4 VGPRs)
typedef __attribute__((ext_vector_type(4))) float f32x4;
typedef __attribute__((ext_vector_type(16))) float f32x16;   // 32x32 MFMA acc
typedef __attribute__((ext_vector_type(4))) unsigned short us4;

__device__ __forceinline__ unsigned short f2b(float f) {
    union { float f; unsigned u; } v; v.f = f;
    return (unsigned short)((v.u + 0x7FFFu + ((v.u >> 16) & 1u)) >> 16);  // RNE
}
__device__ __forceinline__ float b2f(unsigned short h) {
    union { unsigned u; float f; } v; v.u = ((unsigned)h) << 16;
    return v.f;
}
__device__ __forceinline__ unsigned cvtpk(float lo, float hi) {   // RNE pack
    unsigned r;
    asm("v_cvt_pk_bf16_f32 %0, %1, %2" : "=v"(r) : "v"(lo), "v"(hi));
    return r;
}
__device__ __forceinline__ void lds16(const void* g, void* l) {
    __builtin_amdgcn_global_load_lds((const __attribute__((address_space(1))) void*)g,
                                     (__attribute__((address_space(3))) void*)l, 16, 0, 0);
}

// ---------------------------------------------------------------------------
// gemm1_fused: V = conv(x @ W1^T), fully self-contained (2-kernel plan).
//   R14-verified core: BM=BN=128, BK=64, 8 waves = 2x2 spatial x 2 K-halves,
//   32x32x16 MFMA, A (=x) staged raw fp32 via gload_lds + cvtpk-on-read,
//   3-buffer counted-vmcnt pipeline, XOR swizzles, XCD remap, K-split merge,
//   halo fragment + column-major-LDS FIR epilogue.
//   NEW: B (=W1 panel) converted ON THE FLY -- panel source is block-uniform
//   (n0<256 ? Wv : Wq, 128-row panels never straddle row 256). B is
//   reg-staged: global fp32 -> 2 static reg banks -> cvtpk -> ds_write bf16,
//   3 tiles deep (GLB at t+3, DSWB at t+1). Per-iter queue (all waves):
//   [HALO(t+1)] stageA(t+2) DSWB(t+1){auto-waits its regs} GLB(t+3)
//   compute(t) -> explicit s_waitcnt vmcnt(12) drains exactly A(t+1)
//   (12 = A(t+2)4 + B(t+3)4 + 4 younger; halo waves drain B(t+2) early,
//   harmless); lgkmcnt(0) covers the ds_writes; then s_barrier.
//   Taps/beff/corr computed INLINE per-thread in the FIR epilogue (no
//   precomputed H/Beff/Corr buffers, no wprep kernel).
// ---------------------------------------------------------------------------
__global__ __launch_bounds__(512, 2) void gemm1_fused(
    const float* __restrict__ Af, const float* __restrict__ Wq,
    const float* __restrict__ Wv,
    unsigned short* __restrict__ V,
    const float* __restrict__ q3w, const float* __restrict__ q3b,
    const float* __restrict__ v3w, const float* __restrict__ v3b,
    const float* __restrict__ q5w, const float* __restrict__ q5b,
    const float* __restrict__ v5w, const float* __restrict__ v5b,
    const float* __restrict__ q7w, const float* __restrict__ q7b,
    const float* __restrict__ v7w, const float* __restrict__ v7b)
{
    constexpr int ABUF = 49152, ABYT = 32768;
    __shared__ uint8_t sh[3 * ABUF];   // 144KB -> 1 block/CU

    int orig = blockIdx.y * 8 + blockIdx.x;
    int wg   = (orig & 7) * 32 + (orig >> 3);
    const int m0 = (wg >> 3) * 128, n0 = (wg & 7) * 128;
    const bool fir = (n0 >= 256);
    const int  m0h = (m0 == 0) ? 0 : (m0 - 32);      // halo base (clamped)
    const int  lbase = m0 & (L_SEQ - 1);

    const int tid  = threadIdx.x;
    const int wid  = tid >> 6;
    const int lane = tid & 63;
    const int wr   = wid >> 2;
    const int wc   = (wid >> 1) & 1;
    const int kh   = wid & 1;
    const int l31  = lane & 31, hi = lane >> 5;
    const bool firw = fir && (wr == 0);

    f32x16 acc[2][2] = {};
    f32x16 hacc[2] = {};

    // ---- B on-the-fly: block-uniform source, reg-staged in 2 banks ----
    const float* Wsrc = (n0 < 256) ? Wv : Wq;        // stitched W1 panel
    const int r0  = tid >> 3, cg0 = tid & 7;         // thread's 2 B-chunks
    const float* Bg0 = Wsrc + (size_t)(n0 + r0) * EDIM + cg0 * 8;
    const float* Bg1 = Bg0 + (size_t)64 * EDIM;      // row r0+64
    const int dB0 = r0 * 64 + ((cg0 ^ (r0 & 7)) * 8);
    const int dB1 = (64 + r0) * 64 + ((cg0 ^ (r0 & 7)) * 8);
    f32x4 bA0_0, bB0_0, bA1_0, bB1_0;                // bank 0
    f32x4 bA0_1, bB0_1, bA1_1, bB1_1;                // bank 1

#define GLB(BK, t) do {                                                       \
        bA0_##BK = *(const f32x4*)(Bg0 + (t) * 64);                           \
        bB0_##BK = *(const f32x4*)(Bg0 + (t) * 64 + 4);                       \
        bA1_##BK = *(const f32x4*)(Bg1 + (t) * 64);                           \
        bB1_##BK = *(const f32x4*)(Bg1 + (t) * 64 + 4);                       \
    } while (0)
#define DSWB(BK, buf) do {                                                    \
        unsigned short* Bl = (unsigned short*)(sh + (buf) * ABUF + ABYT);     \
        union { unsigned u[4]; bf16x8 v; } u0, u1;                            \
        u0.u[0] = cvtpk(bA0_##BK[0], bA0_##BK[1]);                            \
        u0.u[1] = cvtpk(bA0_##BK[2], bA0_##BK[3]);                            \
        u0.u[2] = cvtpk(bB0_##BK[0], bB0_##BK[1]);                            \
        u0.u[3] = cvtpk(bB0_##BK[2], bB0_##BK[3]);                            \
        u1.u[0] = cvtpk(bA1_##BK[0], bA1_##BK[1]);                            \
        u1.u[1] = cvtpk(bA1_##BK[2], bA1_##BK[3]);                            \
        u1.u[2] = cvtpk(bB1_##BK[0], bB1_##BK[1]);                            \
        u1.u[3] = cvtpk(bB1_##BK[2], bB1_##BK[3]);                            \
        *(bf16x8*)(Bl + dB0) = u0.v;                                          \
        *(bf16x8*)(Bl + dB1) = u1.v;                                          \
    } while (0)

    // halo register banks (static names, rule #20)
    f32x4 h0s0a = {}, h0s0b = {}, h0s1a = {}, h0s1b = {};
    f32x4 h1s0a = {}, h1s0b = {}, h1s1a = {}, h1s1b = {};
    const float* hrow = Af + (size_t)(m0h + l31) * EDIM + kh * 32 + hi * 8;

#define HALOLOAD(B, t) do { if (firw) {                                       \
        const float* hp = hrow + (t) * 64;                                    \
        h##B##s0a = *(const f32x4*)(hp);      h##B##s0b = *(const f32x4*)(hp + 4);  \
        h##B##s1a = *(const f32x4*)(hp + 16); h##B##s1b = *(const f32x4*)(hp + 20); } } while (0)

    auto stage_a = [&](int buf, int t) {
        uint8_t* Abase = sh + buf * ABUF;
        const float* Asrc = Af + (size_t)m0 * EDIM + t * 64;
#pragma unroll
        for (int j = 0; j < 4; ++j) {
            int slot = j * 512 + tid;
            int row = slot >> 4, c = (slot & 15) ^ (row & 15);
            lds16(Asrc + (size_t)row * EDIM + c * 4, Abase + j * 8192 + wid * 1024);
        }
    };

    auto compute = [&](int buf, f32x4 hs0a, f32x4 hs0b, f32x4 hs1a, f32x4 hs1b) {
        const uint8_t* Abase = sh + buf * ABUF;
        const unsigned short* bs = (const unsigned short*)(Abase + ABYT);
#pragma unroll
        for (int s = 0; s < 2; ++s) {                  // two K=16 slabs
            bf16x8 a[2], b[2];
#pragma unroll
            for (int mi = 0; mi < 2; ++mi) {
                int row = wr * 64 + mi * 32 + l31;
                const float* as = (const float*)Abase;
                int c0 = kh * 8 + s * 4 + hi * 2;
                f32x4 lo = *(const f32x4*)(as + row * 64 + ((c0 ^ (row & 15)) * 4));
                f32x4 h4 = *(const f32x4*)(as + row * 64 + (((c0 + 1) ^ (row & 15)) * 4));
                union { unsigned u[4]; bf16x8 v; } fu;
                fu.u[0] = cvtpk(lo[0], lo[1]); fu.u[1] = cvtpk(lo[2], lo[3]);
                fu.u[2] = cvtpk(h4[0], h4[1]); fu.u[3] = cvtpk(h4[2], h4[3]);
                a[mi] = fu.v;
            }
#pragma unroll
            for (int ni = 0; ni < 2; ++ni) {
                int row = wc * 64 + ni * 32 + l31;
                int cg = kh * 4 + s * 2 + hi;
                b[ni] = *(const bf16x8*)(bs + row * 64 + ((cg ^ (row & 7)) * 8));
            }
#pragma unroll
            for (int mi = 0; mi < 2; ++mi)
#pragma unroll
                for (int ni = 0; ni < 2; ++ni)
                    acc[mi][ni] = __builtin_amdgcn_mfma_f32_32x32x16_bf16(a[mi], b[ni], acc[mi][ni], 0, 0, 0);
            if (firw) {                                 // halo 32x64 fragment
                f32x4 pa = s ? hs1a : hs0a, pb = s ? hs1b : hs0b;
                union { unsigned u[4]; bf16x8 v; } hu;
                hu.u[0] = cvtpk(pa[0], pa[1]); hu.u[1] = cvtpk(pa[2], pa[3]);
                hu.u[2] = cvtpk(pb[0], pb[1]); hu.u[3] = cvtpk(pb[2], pb[3]);
                hacc[0] = __builtin_amdgcn_mfma_f32_32x32x16_bf16(hu.v, b[0], hacc[0], 0, 0, 0);
                hacc[1] = __builtin_amdgcn_mfma_f32_32x32x16_bf16(hu.v, b[1], hacc[1], 0, 0, 0);
            }
        }
    };

    const int NT = EDIM >> 6;   // 16 K-tiles (even)
    // prologue: banks {B0->bk0, B1->bk1}; buf0 <- A0,B0; buf1 <- A1; bk0 <- B2
    HALOLOAD(0, 0);
    GLB(0, 0);
    stage_a(0, 0);
    GLB(1, 1);
    stage_a(1, 1);
    DSWB(0, 0);                // auto-waits bank0 (B0) regs only
    GLB(0, 2);
    asm volatile("s_waitcnt vmcnt(12) lgkmcnt(0)" ::: "memory");  // A0 landed
    __builtin_amdgcn_s_barrier();
    asm volatile("" ::: "memory");

    for (int tt = 0; tt < NT; tt += 2) {
        // ---- t = tt (even): halo bank0 computes, B-bank1 writes ----
        HALOLOAD(1, tt + 1);
        if (tt + 2 < NT) stage_a((tt + 2) % 3, tt + 2);
        if (tt + 1 < NT) DSWB(1, (tt + 1) % 3);
        if (tt + 3 < NT) GLB(1, tt + 3);
        compute(tt % 3, h0s0a, h0s0b, h0s1a, h0s1b);
        {
            if (tt + 3 < NT) asm volatile("s_waitcnt vmcnt(12) lgkmcnt(0)" ::: "memory");
            else             asm volatile("s_waitcnt vmcnt(0) lgkmcnt(0)" ::: "memory");
            __builtin_amdgcn_s_barrier();
            asm volatile("" ::: "memory");
        }
        // ---- t = tt+1 (odd): halo bank1 computes, B-bank0 writes ----
        HALOLOAD(0, tt + 2);
        if (tt + 3 < NT) stage_a((tt + 3) % 3, tt + 3);
        if (tt + 2 < NT) DSWB(0, (tt + 2) % 3);
        if (tt + 4 < NT) GLB(0, tt + 4);
        compute((tt + 1) % 3, h1s0a, h1s0b, h1s1a, h1s1b);
        if (tt + 2 < NT) {
            if (tt + 4 < NT) asm volatile("s_waitcnt vmcnt(12) lgkmcnt(0)" ::: "memory");
            else             asm volatile("s_waitcnt vmcnt(0) lgkmcnt(0)" ::: "memory");
            __builtin_amdgcn_s_barrier();
            asm volatile("" ::: "memory");
        }
    }
#undef HALOLOAD
#undef GLB
#undef DSWB

    // ---- K-split merge + fused FIR epilogue (R14-verified layout) ----
    __syncthreads();   // all MFMA reads of sh complete before overwrite
    float* Mg = (float*)sh;                 // 64KB quads + 16KB halo
    const int mgbase = (wr * 2 + wc) * 4096;
    if (kh) {
#pragma unroll
        for (int mi = 0; mi < 2; ++mi)
#pragma unroll
            for (int ni = 0; ni < 2; ++ni) {
                int col = ni * 32 + l31;
#pragma unroll
                for (int q = 0; q < 4; ++q) {
                    int grp = mi * 8 + 2 * q + hi;
                    int adr = mgbase + col * 64 + (((grp) ^ (col & 15)) << 2);
                    f32x4 v;
                    v[0] = acc[mi][ni][q * 4 + 0]; v[1] = acc[mi][ni][q * 4 + 1];
                    v[2] = acc[mi][ni][q * 4 + 2]; v[3] = acc[mi][ni][q * 4 + 3];
                    *(f32x4*)(Mg + adr) = v;
                }
            }
        if (firw) {
#pragma unroll
            for (int ni = 0; ni < 2; ++ni) {
                int hcol = ni * 32 + l31;
#pragma unroll
                for (int q = 0; q < 4; ++q) {
                    int hg = 2 * q + hi;
                    int adr = 16384 + wc * 2048 + hcol * 32 + ((hg ^ (hcol & 7)) << 2);
                    f32x4 v;
                    v[0] = hacc[ni][q * 4 + 0]; v[1] = hacc[ni][q * 4 + 1];
                    v[2] = hacc[ni][q * 4 + 2]; v[3] = hacc[ni][q * 4 + 3];
                    *(f32x4*)(Mg + adr) = v;
                }
            }
        }
    }
    __syncthreads();
    if (fir) {
        unsigned short* Tl = (unsigned short*)(sh + 81920);   // [col][172] bf16
        if (!kh) {
#pragma unroll
            for (int mi = 0; mi < 2; ++mi)
#pragma unroll
                for (int ni = 0; ni < 2; ++ni) {
                    int col = wc * 64 + ni * 32 + l31;
#pragma unroll
                    for (int q = 0; q < 4; ++q) {
                        int grp = mi * 8 + 2 * q + hi;
                        int adr = mgbase + (ni * 32 + l31) * 64 + (((grp) ^ ((ni * 32 + l31) & 15)) << 2);
                        f32x4 p = *(const f32x4*)(Mg + adr);
                        int Lr = 32 + wr * 64 + mi * 32 + 8 * q + 4 * hi;
                        us4 o;
#pragma unroll
                        for (int j = 0; j < 4; ++j) o[j] = f2b(acc[mi][ni][q * 4 + j] + p[j]);
                        *(us4*)(Tl + col * 172 + Lr) = o;
                    }
                }
            if (wr == 0) {   // halo rows -> local rows 0..31
#pragma unroll
                for (int ni = 0; ni < 2; ++ni) {
                    int hcol = ni * 32 + l31;
                    int col = wc * 64 + hcol;
#pragma unroll
                    for (int q = 0; q < 4; ++q) {
                        int hg = 2 * q + hi;
                        int adr = 16384 + wc * 2048 + hcol * 32 + ((hg ^ (hcol & 7)) << 2);
                        f32x4 p = *(const f32x4*)(Mg + adr);
                        int Lr = 8 * q + 4 * hi;
                        us4 o;
#pragma unroll
                        for (int j = 0; j < 4; ++j) o[j] = f2b(hacc[ni][q * 4 + j] + p[j]);
                        *(us4*)(Tl + col * 172 + Lr) = o;
                    }
                }
            }
        }
        __syncthreads();
        // FIR with INLINE taps. thread = (col c, row-block rb of 32).
        int c = tid & 127, rb = tid >> 7;
        int ch = n0 + c - 256;                 // [0,768)
        int g = ch >> 8, d = ch & 63, k = 3 + 2 * g;
        const float* qw = (g == 0) ? q3w : (g == 1) ? q5w : q7w;
        const float* qb = (g == 0) ? q3b : (g == 1) ? q5b : q7b;
        const float* vw = (g == 0) ? v3w : (g == 1) ? v5w : v7w;
        const float* vb = (g == 0) ? v3b : (g == 1) ? v5b : v7b;
        float hq[7], hv[7];
#pragma unroll
        for (int i = 0; i < 7; ++i) { hq[i] = 0.f; hv[i] = 0.f; }
        for (int i = 0; i < k; ++i) {
            hq[i] = qw[d * k + (k - 1 - i)];
            hv[i] = vw[d * k + (k - 1 - i)];
        }
        float h[13];
#pragma unroll
        for (int i = 0; i < 13; ++i) h[i] = 0.f;
#pragma unroll
        for (int a = 0; a < 7; ++a)
#pragma unroll
            for (int b = 0; b < 7; ++b)
                h[a + b] += hq[a] * hv[b];
        float sv = 0.f;
        for (int j = 0; j < k; ++j) sv += vw[d * k + j];
        float beff = qb[d] * sv + vb[d];
        float qbd = qb[d];
        float csum[6];                         // corr[l] = qbd * sum_{i>l} hv[i]
        {
            float s2 = 0.f;
#pragma unroll
            for (int l = 5; l >= 0; --l) { s2 += hv[l + 1]; csum[l] = s2; }
        }
        const unsigned short* wp = Tl + c * 172 + 20 + rb * 32;
        float wf[44];
#pragma unroll
        for (int j = 0; j < 11; ++j) {
            us4 t4 = *(const us4*)(wp + j * 4);
            wf[j * 4 + 0] = b2f(t4[0]); wf[j * 4 + 1] = b2f(t4[1]);
            wf[j * 4 + 2] = b2f(t4[2]); wf[j * 4 + 3] = b2f(t4[3]);
        }
        if (lbase == 0 && rb == 0) {      // batch start: pre-batch rows = 0
#pragma unroll
            for (int j = 0; j < 12; ++j) wf[j] = 0.f;
        }
        unsigned short* vp = V + (size_t)(m0 + rb * 32) * EDIM + n0 + c;
#pragma unroll
        for (int rr = 0; rr < 32; ++rr) {
            float s = beff;
#pragma unroll
            for (int i = 0; i < 13; ++i) s += h[i] * wf[12 + rr - i];
            int l = lbase + rb * 32 + rr;
            if (l < 6) s -= qbd * csum[l];    // bias boundary correction
            vp[(size_t)rr * EDIM] = f2b(s);
        }
    } else {
        // pass-through block: V = T directly
        if (!kh) {
#pragma unroll
            for (int mi = 0; mi < 2; ++mi) {
#pragma unroll
                for (int ni = 0; ni < 2; ++ni) {
                    int col = ni * 32 + l31;
                    int gcol = n0 + wc * 64 + col;
#pragma unroll
                    for (int q = 0; q < 4; ++q) {
                        int grp = mi * 8 + 2 * q + hi;
                        int adr = mgbase + col * 64 + (((grp) ^ (col & 15)) << 2);
                        f32x4 p = *(const f32x4*)(Mg + adr);
                        int rowb = m0 + wr * 64 + mi * 32 + 8 * q + 4 * hi;
#pragma unroll
                        for (int j = 0; j < 4; ++j)
                            V[(size_t)(rowb + j) * EDIM + gcol] = f2b(acc[mi][ni][q * 4 + j] + p[j]);
                    }
                }
            }
        }
    }
}

// ---------------------------------------------------------------------------
// gemm2: out = V @ Wo^T + bo, with Wo converted ON THE FLY (no Wob buffer).
//   Mirror of the verified TA=1 config: A = V bf16 gload (16KB/buf),
//   B = Wo raw fp32 gload (32KB/buf, pre-swizzled src, cvtpk on fragment
//   read). 48KB x 3 bufs = 144KB, depth 2, steady vmcnt(6). K-split merge,
//   f32 store + bias.  (R10/R14-verified core.)
// ---------------------------------------------------------------------------
__global__ __launch_bounds__(512, 2) void gemm2_f(
    const unsigned short* __restrict__ Ab, const float* __restrict__ Wo,
    float* __restrict__ Cf, const float* __restrict__ bias)
{
    constexpr int ABUF = 49152, ABYT = 16384;   // A bf16 16KB, B fp32 32KB
    __shared__ uint8_t sh[3 * ABUF];            // 144KB

    int orig = blockIdx.y * 8 + blockIdx.x;
    int wg   = (orig & 7) * 32 + (orig >> 3);
    const int m0 = (wg >> 3) * 128, n0 = (wg & 7) * 128;

    const int tid  = threadIdx.x;
    const int wid  = tid >> 6;
    const int lane = tid & 63;
    const int wr   = wid >> 2;
    const int wc   = (wid >> 1) & 1;
    const int kh   = wid & 1;
    const int l31  = lane & 31, hi = lane >> 5;

    f32x16 acc[2][2] = {};

    auto stage = [&](int buf, int t) {
        uint8_t* Abase = sh + buf * ABUF;
        uint8_t* Bbase = Abase + ABYT;
        const unsigned short* Asrc = Ab + (size_t)m0 * EDIM + t * 64;
#pragma unroll
        for (int j = 0; j < 2; ++j) {
            int slot = j * 512 + tid;
            int row = slot >> 3, c = (slot & 7) ^ (row & 7);
            lds16(Asrc + (size_t)row * EDIM + c * 8, Abase + j * 8192 + wid * 1024);
        }
        const float* Bsrc = Wo + (size_t)n0 * EDIM + t * 64;
#pragma unroll
        for (int j = 0; j < 4; ++j) {
            int slot = j * 512 + tid;
            int row = slot >> 4, c = (slot & 15) ^ (row & 15);
            lds16(Bsrc + (size_t)row * EDIM + c * 4, Bbase + j * 8192 + wid * 1024);
        }
    };

    auto compute = [&](int buf) {
        const uint8_t* Abase = sh + buf * ABUF;
        const unsigned short* as = (const unsigned short*)Abase;
        const float* bsf = (const float*)(Abase + ABYT);
#pragma unroll
        for (int s = 0; s < 2; ++s) {
            bf16x8 a[2], b[2];
#pragma unroll
            for (int mi = 0; mi < 2; ++mi) {
                int row = wr * 64 + mi * 32 + l31;
                int cg = kh * 4 + s * 2 + hi;
                a[mi] = *(const bf16x8*)(as + row * 64 + ((cg ^ (row & 7)) * 8));
            }
#pragma unroll
            for (int ni = 0; ni < 2; ++ni) {
                int row = wc * 64 + ni * 32 + l31;
                int c0 = kh * 8 + s * 4 + hi * 2;
                f32x4 lo = *(const f32x4*)(bsf + row * 64 + ((c0 ^ (row & 15)) * 4));
                f32x4 h4 = *(const f32x4*)(bsf + row * 64 + (((c0 + 1) ^ (row & 15)) * 4));
                union { unsigned u[4]; bf16x8 v; } fu;
                fu.u[0] = cvtpk(lo[0], lo[1]); fu.u[1] = cvtpk(lo[2], lo[3]);
                fu.u[2] = cvtpk(h4[0], h4[1]); fu.u[3] = cvtpk(h4[2], h4[3]);
                b[ni] = fu.v;
            }
#pragma unroll
            for (int mi = 0; mi < 2; ++mi)
#pragma unroll
                for (int ni = 0; ni < 2; ++ni)
                    acc[mi][ni] = __builtin_amdgcn_mfma_f32_32x32x16_bf16(a[mi], b[ni], acc[mi][ni], 0, 0, 0);
        }
    };

    const int NT = EDIM >> 6;
    stage(0, 0);
    stage(1, 1);
    asm volatile("s_waitcnt vmcnt(6)" ::: "memory");
    __builtin_amdgcn_s_barrier();
    asm volatile("" ::: "memory");

    for (int t = 0; t < NT; ++t) {
        if (t + 2 < NT) stage((t + 2) % 3, t + 2);
        compute(t % 3);
        if (t + 1 < NT) {
            if (t + 2 < NT) asm volatile("s_waitcnt vmcnt(6)" ::: "memory");
            else            asm volatile("s_waitcnt vmcnt(0)" ::: "memory");
            __builtin_amdgcn_s_barrier();
            asm volatile("" ::: "memory");
        }
    }

    __syncthreads();
    float* Mg = (float*)sh;            // 64KB
    const int mgbase = (wr * 2 + wc) * 4096;
    if (kh) {
#pragma unroll
        for (int mi = 0; mi < 2; ++mi)
#pragma unroll
            for (int ni = 0; ni < 2; ++ni) {
                int col = ni * 32 + l31;
#pragma unroll
                for (int q = 0; q < 4; ++q) {
                    int grp = mi * 8 + 2 * q + hi;
                    int adr = mgbase + col * 64 + (((grp) ^ (col & 15)) << 2);
                    f32x4 v;
                    v[0] = acc[mi][ni][q * 4 + 0]; v[1] = acc[mi][ni][q * 4 + 1];
                    v[2] = acc[mi][ni][q * 4 + 2]; v[3] = acc[mi][ni][q * 4 + 3];
                    *(f32x4*)(Mg + adr) = v;
                }
            }
    }
    __syncthreads();
    if (!kh) {
#pragma unroll
        for (int mi = 0; mi < 2; ++mi) {
#pragma unroll
            for (int ni = 0; ni < 2; ++ni) {
                int col = ni * 32 + l31;
                int gcol = n0 + wc * 64 + col;
#pragma unroll
                for (int q = 0; q < 4; ++q) {
                    int grp = mi * 8 + 2 * q + hi;
                    int adr = mgbase + col * 64 + (((grp) ^ (col & 15)) << 2);
                    f32x4 p = *(const f32x4*)(Mg + adr);
                    int rowb = m0 + wr * 64 + mi * 32 + 8 * q + 4 * hi;
#pragma unroll
                    for (int j = 0; j < 4; ++j)
                        Cf[(size_t)(rowb + j) * EDIM + gcol] = acc[mi][ni][q * 4 + j] + p[j] + bias[gcol];
                }
            }
        }
    }
}

// ---------------------------------------------------------------------------
extern "C" void kernel_launch(void* const* d_in, const int* in_sizes, int n_in,
                              void* d_out, int out_size, void* d_ws, size_t ws_size,
                              hipStream_t stream)
{
    const float* x  = (const float*)d_in[0];
    const float* Wq = (const float*)d_in[1];
    // d_in[2] = Wk (dead: attention output is multiplied by 0.0)
    const float* Wv = (const float*)d_in[3];
    const float* Wo = (const float*)d_in[4];
    const float* bo = (const float*)d_in[5];

    unsigned short* V = (unsigned short*)d_ws;   // 8 MB, only workspace used

    dim3 gg(EDIM / 128, MTOT / 128);   // (8, 32) = 256 blocks
    // kernel 1: V = conv(x @ W1^T); W1 stitched+converted on the fly,
    // taps computed inline. No prep pass, no T round-trip.
    gemm1_fused<<<gg, 512, 0, stream>>>(
        x, Wq, Wv, V,
        (const float*)d_in[6],  (const float*)d_in[7],
        (const float*)d_in[10], (const float*)d_in[11],
        (const float*)d_in[12], (const float*)d_in[13],
        (const float*)d_in[16], (const float*)d_in[17],
        (const float*)d_in[18], (const float*)d_in[19],
        (const float*)d_in[22], (const float*)d_in[23]);

    // kernel 2: out = V @ Wo^T + bo; Wo converted on the fly.
    gemm2_f<<<gg, 512, 0, stream>>>(V, Wo, (float*)d_out, bo);
}